// Round 4
// baseline (264.732 us; speedup 1.0000x reference)
//
#include <hip/hip_runtime.h>
#include <hip/hip_bf16.h>
#include <cmath>

// ---------------------------------------------------------------------------
// Causal single-head self-attention, B=4 T=2048 C=1024, fp32 in/out,
// bf16 MFMA internally.
// R1: LDS xor-swizzle (conflicts -> 0), causal tile skip + K-cap.
// R2: fused QKV projection (N=3072, V transposed in epilogue), XCD swizzle.
// R7/R8: Wo folded into V projection (out = P@(X@(Wv@Wo))), 70MB ws carve.
// R9:  (a) 8-phase QKV, drain-every-group — slow but SAFE (78.7us).
//      (b) memcpy elimination: WIN (kept).
// R10: counted-vmcnt 8-phase — RACED: staging halves (A rows 0-127/128-255)
//      did not match consumption (wm=(w>>2)*128 made waves 4-7 read A-h1 at
//      g1; wn=(w&3)*64 made half the waves read B-h1 at g1). R9 only passed
//      because its conservative vmcnt forced the whole next tile per group.
// R12: 8-phase retry with ALIGNED fragments: per-wave rows (w>>2)*64 in h0
//      AND 128+(w>>2)*64 in h1; cols (w&3)*32 in h0 AND 128+(w&3)*32 in h1.
//      g1 reads {A-h0,B-h0}, g2 {B-h1}, g3 {A-h1}, g4 none. Waits vmcnt(6)
//      at g1/g2/g4 (verified queue trace), peeled tail. Last chance for the
//      8-phase; revert permanently on failure.
// ---------------------------------------------------------------------------

typedef __attribute__((ext_vector_type(8))) __bf16 bf16x8;
typedef __attribute__((ext_vector_type(8))) short short8;
typedef __attribute__((ext_vector_type(4))) float f32x4;

__device__ __forceinline__ unsigned short f2bf(float f) {
  union { float f; unsigned u; } v; v.f = f;
  unsigned u = v.u;
  u += ((u >> 16) & 1u) + 0x7fffu;   // round-to-nearest-even
  return (unsigned short)(u >> 16);
}
__device__ __forceinline__ float bf2f(unsigned short h) {
  union { unsigned u; float f; } v; v.u = ((unsigned)h) << 16;
  return v.f;
}

#define GLDS(gp, sp)                                                           \
  __builtin_amdgcn_global_load_lds(                                            \
      (const __attribute__((address_space(1))) void*)(gp),                     \
      (__attribute__((address_space(3))) void*)(sp), 16, 0, 0)

// ------------------------------- prep --------------------------------------
__global__ void prep(const float* __restrict__ X,
                     const float* __restrict__ w0, const float* __restrict__ w1,
                     const float* __restrict__ w2, const float* __restrict__ w3,
                     unsigned short* __restrict__ Xb,
                     unsigned short* __restrict__ wcat,   // [2C][C] used
                     unsigned short* __restrict__ wvb,    // [C][C] plain cast
                     unsigned short* __restrict__ wot,    // [C][C] transposed
                     int n) {
  if (blockIdx.z == 2) {  // plain cast Wv
    int bx = blockIdx.x * 32, by = blockIdx.y * 32;
    int tx = threadIdx.x, ty = threadIdx.y;
#pragma unroll
    for (int i = 0; i < 32; i += 8) {
      size_t idx = (size_t)(by + ty + i) * n + bx + tx;
      wvb[idx] = f2bf(w2[idx]);
    }
  } else if (blockIdx.z < 4) {
    const float* src = blockIdx.z == 0 ? w0 : blockIdx.z == 1 ? w1 : w3;
    unsigned short* dst = blockIdx.z == 0 ? wcat
                          : blockIdx.z == 1 ? wcat + (size_t)n * n : wot;
    __shared__ float tile[32][33];
    int bx = blockIdx.x * 32, by = blockIdx.y * 32;
    int tx = threadIdx.x, ty = threadIdx.y;
#pragma unroll
    for (int i = 0; i < 32; i += 8)
      tile[ty + i][tx] = src[(size_t)(by + ty + i) * n + bx + tx];
    __syncthreads();
#pragma unroll
    for (int i = 0; i < 32; i += 8)
      dst[(size_t)(bx + ty + i) * n + by + tx] = f2bf(tile[tx][ty + i]);
  } else {
    const int bid = (blockIdx.z - 4) * 1024 + blockIdx.y * 32 + blockIdx.x;
    const int t = threadIdx.y * 32 + threadIdx.x;
    const int i = (bid * 256 + t) * 4;
    float4 f = *(const float4*)(X + i);
    ushort4 o = make_ushort4(f2bf(f.x), f2bf(f.y), f2bf(f.z), f2bf(f.w));
    *(ushort4*)(Xb + i) = o;
  }
}

// ------------------------------ GEMM (B^T) ---------------------------------
// 128x128 block tile, BK=64, 16x16x32 bf16 MFMA, LDS xor-swizzle (R1).
template <typename OutT, int NW>
__global__ __launch_bounds__(NW * 64, NW / 2)
void gemm_bt(const unsigned short* __restrict__ A, int lda, long long sA,
             const unsigned short* __restrict__ B, int ldb, long long sB,
             OutT* __restrict__ Cp, int ldc, long long sC,
             int K, float alpha, int tri, int kcap, int gx) {
  A  += (long long)blockIdx.z * sA;
  B  += (long long)blockIdx.z * sB;
  Cp += (long long)blockIdx.z * sC;

  int by, bx;
  if (tri) {
    const int idx = blockIdx.x;
    by = (int)((sqrtf(8.f * idx + 1.f) - 1.f) * 0.5f);
    while (by * (by + 1) / 2 > idx) --by;
    while ((by + 1) * (by + 2) / 2 <= idx) ++by;
    bx = idx - by * (by + 1) / 2;
  } else if (gx > 0) {
    const int id = blockIdx.x;
    const int gs = gx * 8;
    const int g = id / gs, r = id - g * gs;
    bx = r >> 3;
    by = g * 8 + (r & 7);
    if (kcap) by = (gridDim.x / gx) - 1 - by;  // heavy rows first
  } else {
    by = blockIdx.y;
    bx = blockIdx.x;
  }
  const int m0 = by * 128;
  const int n0 = bx * 128;
  const int Keff = kcap ? min(K, m0 + 128) : K;

  const int tid  = threadIdx.x;
  const int lane = tid & 63;
  const int w    = tid >> 6;
  const int wm   = (NW == 4) ? (w >> 1) * 64 : (w >> 1) * 32;
  const int wn   = (w & 1) * 64;
  const int quad = lane >> 4;
  const int l16  = lane & 15;
  constexpr int AI = (NW == 4) ? 4 : 2;   // A-fragment count per wave
  constexpr int NR = 128 / (NW * 8);      // staging rounds per tile

  __shared__ unsigned short As[8192];
  __shared__ unsigned short Bs[8192];

  f32x4 acc[AI][4];
#pragma unroll
  for (int i = 0; i < AI; ++i)
#pragma unroll
    for (int j = 0; j < 4; ++j)
      acc[i][j] = (f32x4){0.f, 0.f, 0.f, 0.f};

  const int srow = tid >> 3;
  const int scol = ((tid & 7) ^ (srow & 7)) * 8;
  const unsigned short* gA = A + (long long)(m0 + srow) * lda + scol;
  const unsigned short* gB = B + (long long)(n0 + srow) * ldb + scol;
  const int rsw = l16 & 7;

  for (int kt = 0; kt < Keff; kt += 64) {
    __syncthreads();
#pragma unroll
    for (int r = 0; r < NR; ++r) {
      GLDS(gA + (long long)(r * NW * 8) * lda + kt, As + r * NW * 512 + tid * 8);
      GLDS(gB + (long long)(r * NW * 8) * ldb + kt, Bs + r * NW * 512 + tid * 8);
    }
    __syncthreads();
#pragma unroll
    for (int ks = 0; ks < 2; ++ks) {
      bf16x8 af[AI], bfr[4];
#pragma unroll
      for (int i = 0; i < AI; ++i)
        af[i] = *(const bf16x8*)(As + (wm + i * 16 + l16) * 64 +
                                 ((ks * 4 + quad) ^ rsw) * 8);
#pragma unroll
      for (int j = 0; j < 4; ++j)
        bfr[j] = *(const bf16x8*)(Bs + (wn + j * 16 + l16) * 64 +
                                  ((ks * 4 + quad) ^ rsw) * 8);
#pragma unroll
      for (int i = 0; i < AI; ++i)
#pragma unroll
        for (int j = 0; j < 4; ++j)
          acc[i][j] = __builtin_amdgcn_mfma_f32_16x16x32_bf16(af[i], bfr[j],
                                                              acc[i][j], 0, 0, 0);
    }
  }

  // C/D layout (m89/m91 verified): col = lane&15, row = quad*4 + reg
#pragma unroll
  for (int i = 0; i < AI; ++i) {
#pragma unroll
    for (int j = 0; j < 4; ++j) {
      const int row = m0 + wm + i * 16 + quad * 4;
      const int col = n0 + wn + j * 16 + l16;
#pragma unroll
      for (int r = 0; r < 4; ++r) {
        float v = acc[i][j][r] * alpha;
        if constexpr (sizeof(OutT) == 2)
          Cp[(long long)(row + r) * ldc + col] = (OutT)f2bf(v);
        else
          Cp[(long long)(row + r) * ldc + col] = v;
      }
    }
  }
}

// ----------------- QKV GEMM, 256x256 8-phase schedule (R12) ----------------
// 512 thr / 8 waves, BK=64, 128KB LDS dbuf. Fragment layout ALIGNED with
// staging halves: per-wave M rows (w>>2)*64 (h0) and 128+(w>>2)*64 (h1);
// N cols (w&3)*32 (h0) and 128+(w&3)*32 (h1).
// Group t (buf B_=t&1): g1 reads {A-h0,B-h0} MM(0,0); g2 reads {B-h1}
// MM(0,1); g3 reads {A-h1} MM(1,1); g4 no reads MM(1,0).
// Stages: g1->(t+1)B-h0, g2->(t+1)B-h1, g3->(t+1)A-h1 (buf^1),
// g4->(t+2)A-h0 (buf). Waits vmcnt(6) at g1/g2/g4: each half forced one
// barrier before its reads, 3-4 phases issue->wait slack, never drains to 0.

// STG(tile tt, subtile st in {0:A-h0,1:A-h1,2:B-h0,3:B-h1}, buffer bb)
#define STG(tt, st, bb) do {                                                  \
    const int ld_ = (st) < 2 ? lda : ldb;                                     \
    const unsigned short* gp_ = ((st) < 2 ? gA : gB)                          \
        + (long long)(((st) & 1) * 128) * ld_ + (long long)(tt) * 64;         \
    unsigned short* sp_ = smem + ((bb) << 15) + (((st) >= 2) ? 16384 : 0)     \
        + (((st) & 1) * 128) * 64 + tid * 8;                                  \
    GLDS(gp_, sp_);                                                           \
    GLDS(gp_ + (long long)64 * ld_, sp_ + 4096);                              \
  } while (0)

#define LDA_PH(mh)                                                            \
  _Pragma("unroll") for (int i = 0; i < 4; ++i)                               \
  _Pragma("unroll") for (int ks = 0; ks < 2; ++ks)                            \
    bA[i][ks] = *(const bf16x8*)(Ab + ((mh) * 128 + wm64 + i * 16 + l16) * 64 \
                                 + (((ks * 4 + quad) ^ rsw) * 8));

#define LDB_PH(jh)                                                            \
  _Pragma("unroll") for (int jj = 0; jj < 2; ++jj)                            \
  _Pragma("unroll") for (int ks = 0; ks < 2; ++ks)                            \
    bB[(jh) * 2 + jj][ks] = *(const bf16x8*)(                                 \
        Bb + ((jh) * 128 + wn32 + jj * 16 + l16) * 64 +                       \
        (((ks * 4 + quad) ^ rsw) * 8));

#define MM(mh, jh)                                                            \
  _Pragma("unroll") for (int i = 0; i < 4; ++i)                               \
  _Pragma("unroll") for (int jj = 0; jj < 2; ++jj)                            \
  _Pragma("unroll") for (int ks = 0; ks < 2; ++ks)                            \
    acc[(mh) * 4 + i][(jh) * 2 + jj] =                                        \
        __builtin_amdgcn_mfma_f32_16x16x32_bf16(                              \
            bA[i][ks], bB[(jh) * 2 + jj][ks],                                 \
            acc[(mh) * 4 + i][(jh) * 2 + jj], 0, 0, 0);

#define VMCNT(n) asm volatile("s_waitcnt vmcnt(" #n ")" ::: "memory")
#define SP1 __builtin_amdgcn_s_setprio(1)
#define SP0 __builtin_amdgcn_s_setprio(0)

#define PHASE_SYNC()                                                          \
  __builtin_amdgcn_s_barrier();                                               \
  asm volatile("s_waitcnt lgkmcnt(0)" ::: "memory");                          \
  __builtin_amdgcn_sched_barrier(0);

// GROUP(buffer, stage-stmt g1..g4, wait-stmt g1, g2, g4)
#define GROUP(B_, S1, S2, S3, S4, W1, W2, W4) do {                            \
    const unsigned short* Ab = smem + ((B_) << 15);                           \
    const unsigned short* Bb = Ab + 16384;                                    \
    /* g1: reads A-h0 + B-h0 */                                               \
    LDA_PH(0); LDB_PH(0); S1; W1; PHASE_SYNC();                               \
    SP1; MM(0, 0); SP0;                                                       \
    __builtin_amdgcn_s_barrier();                                             \
    /* g2: reads B-h1 */                                                      \
    LDB_PH(1); S2; W2; PHASE_SYNC();                                          \
    SP1; MM(0, 1); SP0;                                                       \
    __builtin_amdgcn_s_barrier();                                             \
    /* g3: reads A-h1 */                                                      \
    LDA_PH(1); S3; PHASE_SYNC();                                              \
    SP1; MM(1, 1); SP0;                                                       \
    __builtin_amdgcn_s_barrier();                                             \
    /* g4: no reads */                                                        \
    S4; W4; PHASE_SYNC();                                                     \
    SP1; MM(1, 0); SP0;                                                       \
    __builtin_amdgcn_s_barrier();                                             \
  } while (0)

__global__ __launch_bounds__(512, 2)
void gemm_qkv8(const unsigned short* __restrict__ A, int lda,
               const unsigned short* __restrict__ B, int ldb,
               unsigned short* __restrict__ Cp, int K) {
  const int id  = blockIdx.x;
  const int cpx = gridDim.x >> 3;                 // 384/8 = 48
  const int sw  = (id & 7) * cpx + (id >> 3);     // XCD-contiguous chunks
  const int bx  = sw % 12;                        // N/256 = 12
  const int by  = sw / 12;                        // M/256 = 32
  const int m0  = by * 256;
  const int n0  = bx * 256;

  const int tid  = threadIdx.x;
  const int lane = tid & 63;
  const int w    = tid >> 6;
  const int wm64 = (w >> 2) * 64;                 // M sub-pos within each half
  const int wn32 = (w & 3) * 32;                  // N sub-pos within each half
  const int quad = lane >> 4;
  const int l16  = lane & 15;
  const int rsw  = l16 & 7;

  extern __shared__ unsigned short smem[];        // 2 x [A 16384 | B 16384]

  const int srow = tid >> 3;                      // 0..63
  const int scol = ((tid & 7) ^ (srow & 7)) * 8;  // pre-swizzled source col
  const unsigned short* gA = A + (long long)(m0 + srow) * lda + scol;
  const unsigned short* gB = B + (long long)(n0 + srow) * ldb + scol;

  f32x4 acc[8][4];
#pragma unroll
  for (int i = 0; i < 8; ++i)
#pragma unroll
    for (int j = 0; j < 4; ++j)
      acc[i][j] = (f32x4){0.f, 0.f, 0.f, 0.f};

  bf16x8 bA[4][2], bB[4][2];
  const int nt = K >> 6;                          // 16 (even, >= 4)

  // prologue: tile0 {A-h0,B-h0,B-h1,A-h1} + tile1 A-h0; vmcnt(6) forces
  // the 4 oldest = t0 A-h0, B-h0 (exactly g1's reads)
  STG(0, 0, 0); STG(0, 2, 0); STG(0, 3, 0); STG(0, 1, 0);
  STG(1, 0, 1);
  VMCNT(6);
  __builtin_amdgcn_s_barrier();

  // main: groups 0 .. nt-3
  for (int tt = 0; tt < nt - 2; tt += 2) {
    GROUP(0, STG(tt + 1, 2, 1), STG(tt + 1, 3, 1), STG(tt + 1, 1, 1),
          STG(tt + 2, 0, 0), VMCNT(6), VMCNT(6), VMCNT(6));
    GROUP(1, STG(tt + 2, 2, 0), STG(tt + 2, 3, 0), STG(tt + 2, 1, 0),
          STG(tt + 3, 0, 1), VMCNT(6), VMCNT(6), VMCNT(6));
  }
  // tail: group nt-2 (stages tile nt-1 B/A halves; no t+2; g4 vmcnt(4))
  GROUP(0, STG(nt - 1, 2, 1), STG(nt - 1, 3, 1), STG(nt - 1, 1, 1),
        (void)0, VMCNT(6), VMCNT(6), VMCNT(4));
  // tail: group nt-1 (no stages; drain g1 vmcnt(2), g2 vmcnt(0))
  GROUP(1, (void)0, (void)0, (void)0, (void)0, VMCNT(2), VMCNT(0), (void)0);

  // epilogue: Q (col<1024) | K (+8M) | V^T (+16M, Vt[b][c][t])
  // row = m0 + mh*128 + wm64 + i*16 + quad*4 ; col = n0 + jh*128 + wn32
  //       + jj*16 + l16 ; acc[mh*4+i][jh*2+jj]
#pragma unroll
  for (int mi = 0; mi < 8; ++mi) {
#pragma unroll
    for (int nj = 0; nj < 4; ++nj) {
      const int row = m0 + (mi >> 2) * 128 + wm64 + (mi & 3) * 16 + quad * 4;
      const int col = n0 + (nj >> 1) * 128 + wn32 + (nj & 1) * 16 + l16;
      if (col >= 2048) {  // V(=X@Wv@Wo), stored transposed: Vt[b][c][t]
        const int b = row >> 11, t = row & 2047, cv = col - 2048;
        ushort4 o = make_ushort4(f2bf(acc[mi][nj][0]), f2bf(acc[mi][nj][1]),
                                 f2bf(acc[mi][nj][2]), f2bf(acc[mi][nj][3]));
        *(ushort4*)(Cp + 16777216LL + ((long long)(b * 1024 + cv)) * 2048 + t) = o;
      } else {  // Q (col<1024) or K (col in [1024,2048))
        unsigned short* dst = Cp + (col >= 1024 ? 8388608LL - 1024 : 0);
#pragma unroll
        for (int r2 = 0; r2 < 4; ++r2)
          dst[(long long)(row + r2) * 1024 + col] = f2bf(acc[mi][nj][r2]);
      }
    }
  }
}

#undef GROUP
#undef PHASE_SYNC
#undef SP1
#undef SP0
#undef VMCNT
#undef MM
#undef LDB_PH
#undef LDA_PH
#undef STG

// ------------------------- causal softmax (out-of-place) -------------------
__global__ __launch_bounds__(256)
void softmax_causal(const unsigned short* __restrict__ Sin,
                    unsigned short* __restrict__ Sout, int T) {
  const long long row = blockIdx.x;
  const int t = (int)(row & (long long)(T - 1));
  const int limit = ((t >> 7) + 1) << 7;
  const unsigned short* pin = Sin + row * T;
  unsigned short* pout = Sout + row * T;
  const int tid  = threadIdx.x;
  const int base = tid * 8;
  const bool active = base < limit;

  short8 raw = {};
  if (active) raw = *(const short8*)(pin + base);
  float x[8];
  float mx = -1e30f;
#pragma unroll
  for (int j = 0; j < 8; ++j) {
    bool valid = active && (base + j) <= t;
    x[j] = valid ? bf2f((unsigned short)raw[j]) : -1e30f;
    mx = fmaxf(mx, x[j]);
  }
#pragma unroll
  for (int off = 32; off > 0; off >>= 1) mx = fmaxf(mx, __shfl_xor(mx, off));
  __shared__ float red[8];
  const int wv = tid >> 6;
  if ((tid & 63) == 0) red[wv] = mx;
  __syncthreads();
  mx = fmaxf(fmaxf(red[0], red[1]), fmaxf(red[2], red[3]));

  float sum = 0.f;
#pragma unroll
  for (int j = 0; j < 8; ++j) {
    bool valid = active && (base + j) <= t;
    x[j] = valid ? __expf(x[j] - mx) : 0.f;
    sum += x[j];
  }
#pragma unroll
  for (int off = 32; off > 0; off >>= 1) sum += __shfl_xor(sum, off);
  if ((tid & 63) == 0) red[4 + wv] = sum;
  __syncthreads();
  sum = red[4] + red[5] + red[6] + red[7];
  const float inv = 1.f / sum;

  if (active) {
    unsigned short out[8];
#pragma unroll
    for (int j = 0; j < 8; ++j) out[j] = f2bf(x[j] * inv);
    *(short8*)(pout + base) = *(const short8*)out;
  }
}

// ---------------------------------------------------------------------------
extern "C" void kernel_launch(void* const* d_in, const int* in_sizes, int n_in,
                              void* d_out, int out_size, void* d_ws,
                              size_t ws_size, hipStream_t stream) {
  (void)in_sizes; (void)n_in; (void)out_size; (void)ws_size;
  const int Bb = 4, T = 2048, C = 1024;
  const int M = Bb * T;  // 8192

  const float* X  = (const float*)d_in[0];
  const float* Wq = (const float*)d_in[1];
  const float* Wk = (const float*)d_in[2];
  const float* Wv = (const float*)d_in[3];
  const float* Wo = (const float*)d_in[4];

  // ws carve: 70MB (proven budget is >=72). Q/Kb/Vt contiguous triple.
  char* w = (char*)d_ws;
  unsigned short* Wcat = (unsigned short*)w; w += (size_t)3 * C * C * 2;  // 6MB
  unsigned short* Q    = (unsigned short*)w; w += (size_t)M * C * 2;      // 16MB
  unsigned short* Kb   = (unsigned short*)w; w += (size_t)M * C * 2;      // 16MB (Q+8M)
  unsigned short* Vt   = (unsigned short*)w; w += (size_t)M * C * 2;      // 16MB (Q+16M)
  unsigned short* Xb   = (unsigned short*)w; w += (size_t)M * C * 2;      // 16MB
  (void)Kb;
  // d_out (32MB) phases: [Wvb 2MB | Wot 2MB] -> S (bf16 32MB) -> final fp32
  unsigned short* Wvb  = (unsigned short*)d_out;               // Wv, cast only
  unsigned short* Wot  = (unsigned short*)d_out + (size_t)C * C;  // Wo^T
  unsigned short* S    = (unsigned short*)d_out;               // overwrites both
  unsigned short* Sn   = Q;  // normalized P, 32MB over dead Q+Kb (post-QK^T)

  // one-time: allow 128KB dynamic LDS for the 8-phase QKV GEMM
  static int smem_set = 0;
  if (!smem_set) {
    hipFuncSetAttribute(reinterpret_cast<const void*>(gemm_qkv8),
                        hipFuncAttributeMaxDynamicSharedMemorySize, 131072);
    smem_set = 1;
  }

  // prep: Wq->Wcat0, Wk->Wcat1 (T), Wv->Wvb (cast), Wo->Wot (T), X->Xb
  prep<<<dim3(32, 32, 12), dim3(32, 8), 0, stream>>>(X, Wq, Wk, Wv, Wo, Xb,
                                                     Wcat, Wvb, Wot, C);

  // WvoT[n][k] = sum_i Wot[n][i]*Wvb[k][i] = (Wv@Wo)^T[n][k] -> Wcat slot 2
  gemm_bt<unsigned short, 4><<<dim3(C / 128, C / 128, 1), dim3(256), 0, stream>>>(
      Wot, C, 0, Wvb, C, 0, Wcat + (size_t)2 * C * C, C, 0, C, 1.f, 0, 0, 0);

  // fused QKV: [8192 x 3072] = Xb @ Wcat^T-layout (V-slot = Wv@Wo)
  // 256x256 8-phase counted-vmcnt, aligned fragments (R12)
  gemm_qkv8<<<dim3((M / 256) * (3 * C / 256)), dim3(512), 131072, stream>>>(
      Xb, C, Wcat, C, Q, C);

  // S[b] = Q[b] @ K[b]^T / 32 — lower-tri 128-tiles (136 x 4), into d_out
  const int ntri = (T / 128) * (T / 128 + 1) / 2;
  gemm_bt<unsigned short, 8><<<dim3(ntri, 1, Bb), dim3(512), 0, stream>>>(
      Q, C, (long long)T * C, Kb, C, (long long)T * C,
      S, T, (long long)T * T, C, 0.03125f, 1, 0, 0);

  // causal softmax: S (d_out) -> Sn (ws, over dead Q+Kb)
  softmax_causal<<<M, 256, 0, stream>>>(S, Sn, T);

  // FINAL GEMM: Out[b] = P[b] @ (V@Wo)[b] — fp32 straight into d_out (R9b)
  gemm_bt<float, 8><<<dim3((C / 128) * (T / 128), 1, Bb), dim3(512), 0, stream>>>(
      Sn, T, (long long)T * T, Vt, T, (long long)C * T,
      (float*)d_out, C, (long long)T * C, T, 1.f, 0, 1, /*gx=*/C / 128);
}

// Round 6
// 260.810 us; speedup vs baseline: 1.0150x; 1.0150x over previous
//
#include <hip/hip_runtime.h>
#include <hip/hip_bf16.h>
#include <cmath>

// ---------------------------------------------------------------------------
// Causal single-head self-attention, B=4 T=2048 C=1024, fp32 in/out,
// bf16 MFMA internally.
// R1: LDS xor-swizzle (conflicts -> 0), causal tile skip + K-cap.
// R2: fused QKV projection (N=3072, V transposed in epilogue), XCD swizzle.
// R7/R8: Wo folded into V projection (out = P@(X@(Wv@Wo))), 70MB ws carve.
// R9:  (a) 8-phase QKV, drain-every-group — slow but SAFE (78.7us).
//      (b) memcpy elimination: WIN (kept).
// R10: counted-vmcnt 8-phase — RACED: fragment layout misaligned with the
//      staging halves (waves read h1 data in phases where only h0 forced).
// R12: ALIGNED fragments (rows (w>>2)*64 per half, cols (w&3)*32 per half)
//      — PASSED (race fixed) but 100us: VGPR_Count=128 with ~210 live regs
//      (acc 128 + frags 64 + addr) => AGPR-squeeze/spill inside K-loop.
//      launch_bounds(512,2)'s 2-waves/EU target capped the register file
//      for nothing (128KB LDS already limits to 1 block/CU).
// R13: (a) gemm_qkv8 __launch_bounds__(512,1) — free the allocator; same
//      schedule byte-for-byte otherwise (R12 passed => semantics proven).
//      (b) QK^T tri-index XCD-contiguous swizzle (136=8x17, bijective):
//      same-XCD blocks share Q/K panels in L2.
//      Fallback if qkv8 still >=62.6: permanent revert to gemm_qkv.
// R14: R13 was never measured (container infra failure) — resubmitted
//      unchanged.
// ---------------------------------------------------------------------------

typedef __attribute__((ext_vector_type(8))) __bf16 bf16x8;
typedef __attribute__((ext_vector_type(8))) short short8;
typedef __attribute__((ext_vector_type(4))) float f32x4;

__device__ __forceinline__ unsigned short f2bf(float f) {
  union { float f; unsigned u; } v; v.f = f;
  unsigned u = v.u;
  u += ((u >> 16) & 1u) + 0x7fffu;   // round-to-nearest-even
  return (unsigned short)(u >> 16);
}
__device__ __forceinline__ float bf2f(unsigned short h) {
  union { unsigned u; float f; } v; v.u = ((unsigned)h) << 16;
  return v.f;
}

#define GLDS(gp, sp)                                                           \
  __builtin_amdgcn_global_load_lds(                                            \
      (const __attribute__((address_space(1))) void*)(gp),                     \
      (__attribute__((address_space(3))) void*)(sp), 16, 0, 0)

// ------------------------------- prep --------------------------------------
__global__ void prep(const float* __restrict__ X,
                     const float* __restrict__ w0, const float* __restrict__ w1,
                     const float* __restrict__ w2, const float* __restrict__ w3,
                     unsigned short* __restrict__ Xb,
                     unsigned short* __restrict__ wcat,   // [2C][C] used
                     unsigned short* __restrict__ wvb,    // [C][C] plain cast
                     unsigned short* __restrict__ wot,    // [C][C] transposed
                     int n) {
  if (blockIdx.z == 2) {  // plain cast Wv
    int bx = blockIdx.x * 32, by = blockIdx.y * 32;
    int tx = threadIdx.x, ty = threadIdx.y;
#pragma unroll
    for (int i = 0; i < 32; i += 8) {
      size_t idx = (size_t)(by + ty + i) * n + bx + tx;
      wvb[idx] = f2bf(w2[idx]);
    }
  } else if (blockIdx.z < 4) {
    const float* src = blockIdx.z == 0 ? w0 : blockIdx.z == 1 ? w1 : w3;
    unsigned short* dst = blockIdx.z == 0 ? wcat
                          : blockIdx.z == 1 ? wcat + (size_t)n * n : wot;
    __shared__ float tile[32][33];
    int bx = blockIdx.x * 32, by = blockIdx.y * 32;
    int tx = threadIdx.x, ty = threadIdx.y;
#pragma unroll
    for (int i = 0; i < 32; i += 8)
      tile[ty + i][tx] = src[(size_t)(by + ty + i) * n + bx + tx];
    __syncthreads();
#pragma unroll
    for (int i = 0; i < 32; i += 8)
      dst[(size_t)(bx + ty + i) * n + by + tx] = f2bf(tile[tx][ty + i]);
  } else {
    const int bid = (blockIdx.z - 4) * 1024 + blockIdx.y * 32 + blockIdx.x;
    const int t = threadIdx.y * 32 + threadIdx.x;
    const int i = (bid * 256 + t) * 4;
    float4 f = *(const float4*)(X + i);
    ushort4 o = make_ushort4(f2bf(f.x), f2bf(f.y), f2bf(f.z), f2bf(f.w));
    *(ushort4*)(Xb + i) = o;
  }
}

// ------------------------------ GEMM (B^T) ---------------------------------
// 128x128 block tile, BK=64, 16x16x32 bf16 MFMA, LDS xor-swizzle (R1).
template <typename OutT, int NW>
__global__ __launch_bounds__(NW * 64, NW / 2)
void gemm_bt(const unsigned short* __restrict__ A, int lda, long long sA,
             const unsigned short* __restrict__ B, int ldb, long long sB,
             OutT* __restrict__ Cp, int ldc, long long sC,
             int K, float alpha, int tri, int kcap, int gx) {
  A  += (long long)blockIdx.z * sA;
  B  += (long long)blockIdx.z * sB;
  Cp += (long long)blockIdx.z * sC;

  int by, bx;
  if (tri) {
    // XCD-contiguous remap (R13b): gridDim.x % 8 == 0 (136 = 8*17).
    int idx = blockIdx.x;
    idx = (idx & 7) * ((int)gridDim.x >> 3) + (idx >> 3);
    by = (int)((sqrtf(8.f * idx + 1.f) - 1.f) * 0.5f);
    while (by * (by + 1) / 2 > idx) --by;
    while ((by + 1) * (by + 2) / 2 <= idx) ++by;
    bx = idx - by * (by + 1) / 2;
  } else if (gx > 0) {
    const int id = blockIdx.x;
    const int gs = gx * 8;
    const int g = id / gs, r = id - g * gs;
    bx = r >> 3;
    by = g * 8 + (r & 7);
    if (kcap) by = (gridDim.x / gx) - 1 - by;  // heavy rows first
  } else {
    by = blockIdx.y;
    bx = blockIdx.x;
  }
  const int m0 = by * 128;
  const int n0 = bx * 128;
  const int Keff = kcap ? min(K, m0 + 128) : K;

  const int tid  = threadIdx.x;
  const int lane = tid & 63;
  const int w    = tid >> 6;
  const int wm   = (NW == 4) ? (w >> 1) * 64 : (w >> 1) * 32;
  const int wn   = (w & 1) * 64;
  const int quad = lane >> 4;
  const int l16  = lane & 15;
  constexpr int AI = (NW == 4) ? 4 : 2;   // A-fragment count per wave
  constexpr int NR = 128 / (NW * 8);      // staging rounds per tile

  __shared__ unsigned short As[8192];
  __shared__ unsigned short Bs[8192];

  f32x4 acc[AI][4];
#pragma unroll
  for (int i = 0; i < AI; ++i)
#pragma unroll
    for (int j = 0; j < 4; ++j)
      acc[i][j] = (f32x4){0.f, 0.f, 0.f, 0.f};

  const int srow = tid >> 3;
  const int scol = ((tid & 7) ^ (srow & 7)) * 8;
  const unsigned short* gA = A + (long long)(m0 + srow) * lda + scol;
  const unsigned short* gB = B + (long long)(n0 + srow) * ldb + scol;
  const int rsw = l16 & 7;

  for (int kt = 0; kt < Keff; kt += 64) {
    __syncthreads();
#pragma unroll
    for (int r = 0; r < NR; ++r) {
      GLDS(gA + (long long)(r * NW * 8) * lda + kt, As + r * NW * 512 + tid * 8);
      GLDS(gB + (long long)(r * NW * 8) * ldb + kt, Bs + r * NW * 512 + tid * 8);
    }
    __syncthreads();
#pragma unroll
    for (int ks = 0; ks < 2; ++ks) {
      bf16x8 af[AI], bfr[4];
#pragma unroll
      for (int i = 0; i < AI; ++i)
        af[i] = *(const bf16x8*)(As + (wm + i * 16 + l16) * 64 +
                                 ((ks * 4 + quad) ^ rsw) * 8);
#pragma unroll
      for (int j = 0; j < 4; ++j)
        bfr[j] = *(const bf16x8*)(Bs + (wn + j * 16 + l16) * 64 +
                                  ((ks * 4 + quad) ^ rsw) * 8);
#pragma unroll
      for (int i = 0; i < AI; ++i)
#pragma unroll
        for (int j = 0; j < 4; ++j)
          acc[i][j] = __builtin_amdgcn_mfma_f32_16x16x32_bf16(af[i], bfr[j],
                                                              acc[i][j], 0, 0, 0);
    }
  }

  // C/D layout (m89/m91 verified): col = lane&15, row = quad*4 + reg
#pragma unroll
  for (int i = 0; i < AI; ++i) {
#pragma unroll
    for (int j = 0; j < 4; ++j) {
      const int row = m0 + wm + i * 16 + quad * 4;
      const int col = n0 + wn + j * 16 + l16;
#pragma unroll
      for (int r = 0; r < 4; ++r) {
        float v = acc[i][j][r] * alpha;
        if constexpr (sizeof(OutT) == 2)
          Cp[(long long)(row + r) * ldc + col] = (OutT)f2bf(v);
        else
          Cp[(long long)(row + r) * ldc + col] = v;
      }
    }
  }
}

// ----------------- QKV GEMM, 256x256 8-phase schedule (R12/R13) ------------
// 512 thr / 8 waves, BK=64, 128KB LDS dbuf. Fragment layout ALIGNED with
// staging halves: per-wave M rows (w>>2)*64 (h0) and 128+(w>>2)*64 (h1);
// N cols (w&3)*32 (h0) and 128+(w&3)*32 (h1).
// Group t (buf B_=t&1): g1 reads {A-h0,B-h0} MM(0,0); g2 reads {B-h1}
// MM(0,1); g3 reads {A-h1} MM(1,1); g4 no reads MM(1,0).
// Stages: g1->(t+1)B-h0, g2->(t+1)B-h1, g3->(t+1)A-h1 (buf^1),
// g4->(t+2)A-h0 (buf). Waits vmcnt(6) at g1/g2/g4.
// R13a: __launch_bounds__(512,1) — 128KB LDS caps at 1 block/CU anyway;
// the old (512,2) squeezed ~210 live regs into a 128-VGPR arch file.

// STG(tile tt, subtile st in {0:A-h0,1:A-h1,2:B-h0,3:B-h1}, buffer bb)
#define STG(tt, st, bb) do {                                                  \
    const int ld_ = (st) < 2 ? lda : ldb;                                     \
    const unsigned short* gp_ = ((st) < 2 ? gA : gB)                          \
        + (long long)(((st) & 1) * 128) * ld_ + (long long)(tt) * 64;         \
    unsigned short* sp_ = smem + ((bb) << 15) + (((st) >= 2) ? 16384 : 0)     \
        + (((st) & 1) * 128) * 64 + tid * 8;                                  \
    GLDS(gp_, sp_);                                                           \
    GLDS(gp_ + (long long)64 * ld_, sp_ + 4096);                              \
  } while (0)

#define LDA_PH(mh)                                                            \
  _Pragma("unroll") for (int i = 0; i < 4; ++i)                               \
  _Pragma("unroll") for (int ks = 0; ks < 2; ++ks)                            \
    bA[i][ks] = *(const bf16x8*)(Ab + ((mh) * 128 + wm64 + i * 16 + l16) * 64 \
                                 + (((ks * 4 + quad) ^ rsw) * 8));

#define LDB_PH(jh)                                                            \
  _Pragma("unroll") for (int jj = 0; jj < 2; ++jj)                            \
  _Pragma("unroll") for (int ks = 0; ks < 2; ++ks)                            \
    bB[(jh) * 2 + jj][ks] = *(const bf16x8*)(                                 \
        Bb + ((jh) * 128 + wn32 + jj * 16 + l16) * 64 +                       \
        (((ks * 4 + quad) ^ rsw) * 8));

#define MM(mh, jh)                                                            \
  _Pragma("unroll") for (int i = 0; i < 4; ++i)                               \
  _Pragma("unroll") for (int jj = 0; jj < 2; ++jj)                            \
  _Pragma("unroll") for (int ks = 0; ks < 2; ++ks)                            \
    acc[(mh) * 4 + i][(jh) * 2 + jj] =                                        \
        __builtin_amdgcn_mfma_f32_16x16x32_bf16(                              \
            bA[i][ks], bB[(jh) * 2 + jj][ks],                                 \
            acc[(mh) * 4 + i][(jh) * 2 + jj], 0, 0, 0);

#define VMCNT(n) asm volatile("s_waitcnt vmcnt(" #n ")" ::: "memory")
#define SP1 __builtin_amdgcn_s_setprio(1)
#define SP0 __builtin_amdgcn_s_setprio(0)

#define PHASE_SYNC()                                                          \
  __builtin_amdgcn_s_barrier();                                               \
  asm volatile("s_waitcnt lgkmcnt(0)" ::: "memory");                          \
  __builtin_amdgcn_sched_barrier(0);

// GROUP(buffer, stage-stmt g1..g4, wait-stmt g1, g2, g4)
#define GROUP(B_, S1, S2, S3, S4, W1, W2, W4) do {                            \
    const unsigned short* Ab = smem + ((B_) << 15);                           \
    const unsigned short* Bb = Ab + 16384;                                    \
    /* g1: reads A-h0 + B-h0 */                                               \
    LDA_PH(0); LDB_PH(0); S1; W1; PHASE_SYNC();                               \
    SP1; MM(0, 0); SP0;                                                       \
    __builtin_amdgcn_s_barrier();                                             \
    /* g2: reads B-h1 */                                                      \
    LDB_PH(1); S2; W2; PHASE_SYNC();                                          \
    SP1; MM(0, 1); SP0;                                                       \
    __builtin_amdgcn_s_barrier();                                             \
    /* g3: reads A-h1 */                                                      \
    LDA_PH(1); S3; PHASE_SYNC();                                              \
    SP1; MM(1, 1); SP0;                                                       \
    __builtin_amdgcn_s_barrier();                                             \
    /* g4: no reads */                                                        \
    S4; W4; PHASE_SYNC();                                                     \
    SP1; MM(1, 0); SP0;                                                       \
    __builtin_amdgcn_s_barrier();                                             \
  } while (0)

__global__ __launch_bounds__(512, 1)
void gemm_qkv8(const unsigned short* __restrict__ A, int lda,
               const unsigned short* __restrict__ B, int ldb,
               unsigned short* __restrict__ Cp, int K) {
  const int id  = blockIdx.x;
  const int cpx = gridDim.x >> 3;                 // 384/8 = 48
  const int sw  = (id & 7) * cpx + (id >> 3);     // XCD-contiguous chunks
  const int bx  = sw % 12;                        // N/256 = 12
  const int by  = sw / 12;                        // M/256 = 32
  const int m0  = by * 256;
  const int n0  = bx * 256;

  const int tid  = threadIdx.x;
  const int lane = tid & 63;
  const int w    = tid >> 6;
  const int wm64 = (w >> 2) * 64;                 // M sub-pos within each half
  const int wn32 = (w & 3) * 32;                  // N sub-pos within each half
  const int quad = lane >> 4;
  const int l16  = lane & 15;
  const int rsw  = l16 & 7;

  extern __shared__ unsigned short smem[];        // 2 x [A 16384 | B 16384]

  const int srow = tid >> 3;                      // 0..63
  const int scol = ((tid & 7) ^ (srow & 7)) * 8;  // pre-swizzled source col
  const unsigned short* gA = A + (long long)(m0 + srow) * lda + scol;
  const unsigned short* gB = B + (long long)(n0 + srow) * ldb + scol;

  f32x4 acc[8][4];
#pragma unroll
  for (int i = 0; i < 8; ++i)
#pragma unroll
    for (int j = 0; j < 4; ++j)
      acc[i][j] = (f32x4){0.f, 0.f, 0.f, 0.f};

  bf16x8 bA[4][2], bB[4][2];
  const int nt = K >> 6;                          // 16 (even, >= 4)

  // prologue: tile0 {A-h0,B-h0,B-h1,A-h1} + tile1 A-h0; vmcnt(6) forces
  // the 4 oldest = t0 A-h0, B-h0 (exactly g1's reads)
  STG(0, 0, 0); STG(0, 2, 0); STG(0, 3, 0); STG(0, 1, 0);
  STG(1, 0, 1);
  VMCNT(6);
  __builtin_amdgcn_s_barrier();

  // main: groups 0 .. nt-3
  for (int tt = 0; tt < nt - 2; tt += 2) {
    GROUP(0, STG(tt + 1, 2, 1), STG(tt + 1, 3, 1), STG(tt + 1, 1, 1),
          STG(tt + 2, 0, 0), VMCNT(6), VMCNT(6), VMCNT(6));
    GROUP(1, STG(tt + 2, 2, 0), STG(tt + 2, 3, 0), STG(tt + 2, 1, 0),
          STG(tt + 3, 0, 1), VMCNT(6), VMCNT(6), VMCNT(6));
  }
  // tail: group nt-2 (stages tile nt-1 B/A halves; no t+2; g4 vmcnt(4))
  GROUP(0, STG(nt - 1, 2, 1), STG(nt - 1, 3, 1), STG(nt - 1, 1, 1),
        (void)0, VMCNT(6), VMCNT(6), VMCNT(4));
  // tail: group nt-1 (no stages; drain g1 vmcnt(2), g2 vmcnt(0))
  GROUP(1, (void)0, (void)0, (void)0, (void)0, VMCNT(2), VMCNT(0), (void)0);

  // epilogue: Q (col<1024) | K (+8M) | V^T (+16M, Vt[b][c][t])
  // row = m0 + mh*128 + wm64 + i*16 + quad*4 ; col = n0 + jh*128 + wn32
  //       + jj*16 + l16 ; acc[mh*4+i][jh*2+jj]
#pragma unroll
  for (int mi = 0; mi < 8; ++mi) {
#pragma unroll
    for (int nj = 0; nj < 4; ++nj) {
      const int row = m0 + (mi >> 2) * 128 + wm64 + (mi & 3) * 16 + quad * 4;
      const int col = n0 + (nj >> 1) * 128 + wn32 + (nj & 1) * 16 + l16;
      if (col >= 2048) {  // V(=X@Wv@Wo), stored transposed: Vt[b][c][t]
        const int b = row >> 11, t = row & 2047, cv = col - 2048;
        ushort4 o = make_ushort4(f2bf(acc[mi][nj][0]), f2bf(acc[mi][nj][1]),
                                 f2bf(acc[mi][nj][2]), f2bf(acc[mi][nj][3]));
        *(ushort4*)(Cp + 16777216LL + ((long long)(b * 1024 + cv)) * 2048 + t) = o;
      } else {  // Q (col<1024) or K (col in [1024,2048))
        unsigned short* dst = Cp + (col >= 1024 ? 8388608LL - 1024 : 0);
#pragma unroll
        for (int r2 = 0; r2 < 4; ++r2)
          dst[(long long)(row + r2) * 1024 + col] = f2bf(acc[mi][nj][r2]);
      }
    }
  }
}

#undef GROUP
#undef PHASE_SYNC
#undef SP1
#undef SP0
#undef VMCNT
#undef MM
#undef LDB_PH
#undef LDA_PH
#undef STG

// ------------------------- causal softmax (out-of-place) -------------------
__global__ __launch_bounds__(256)
void softmax_causal(const unsigned short* __restrict__ Sin,
                    unsigned short* __restrict__ Sout, int T) {
  const long long row = blockIdx.x;
  const int t = (int)(row & (long long)(T - 1));
  const int limit = ((t >> 7) + 1) << 7;
  const unsigned short* pin = Sin + row * T;
  unsigned short* pout = Sout + row * T;
  const int tid  = threadIdx.x;
  const int base = tid * 8;
  const bool active = base < limit;

  short8 raw = {};
  if (active) raw = *(const short8*)(pin + base);
  float x[8];
  float mx = -1e30f;
#pragma unroll
  for (int j = 0; j < 8; ++j) {
    bool valid = active && (base + j) <= t;
    x[j] = valid ? bf2f((unsigned short)raw[j]) : -1e30f;
    mx = fmaxf(mx, x[j]);
  }
#pragma unroll
  for (int off = 32; off > 0; off >>= 1) mx = fmaxf(mx, __shfl_xor(mx, off));
  __shared__ float red[8];
  const int wv = tid >> 6;
  if ((tid & 63) == 0) red[wv] = mx;
  __syncthreads();
  mx = fmaxf(fmaxf(red[0], red[1]), fmaxf(red[2], red[3]));

  float sum = 0.f;
#pragma unroll
  for (int j = 0; j < 8; ++j) {
    bool valid = active && (base + j) <= t;
    x[j] = valid ? __expf(x[j] - mx) : 0.f;
    sum += x[j];
  }
#pragma unroll
  for (int off = 32; off > 0; off >>= 1) sum += __shfl_xor(sum, off);
  if ((tid & 63) == 0) red[4 + wv] = sum;
  __syncthreads();
  sum = red[4] + red[5] + red[6] + red[7];
  const float inv = 1.f / sum;

  if (active) {
    unsigned short out[8];
#pragma unroll
    for (int j = 0; j < 8; ++j) out[j] = f2bf(x[j] * inv);
    *(short8*)(pout + base) = *(const short8*)out;
  }
}

// ---------------------------------------------------------------------------
extern "C" void kernel_launch(void* const* d_in, const int* in_sizes, int n_in,
                              void* d_out, int out_size, void* d_ws,
                              size_t ws_size, hipStream_t stream) {
  (void)in_sizes; (void)n_in; (void)out_size; (void)ws_size;
  const int Bb = 4, T = 2048, C = 1024;
  const int M = Bb * T;  // 8192

  const float* X  = (const float*)d_in[0];
  const float* Wq = (const float*)d_in[1];
  const float* Wk = (const float*)d_in[2];
  const float* Wv = (const float*)d_in[3];
  const float* Wo = (const float*)d_in[4];

  // ws carve: 70MB (proven budget is >=72). Q/Kb/Vt contiguous triple.
  char* w = (char*)d_ws;
  unsigned short* Wcat = (unsigned short*)w; w += (size_t)3 * C * C * 2;  // 6MB
  unsigned short* Q    = (unsigned short*)w; w += (size_t)M * C * 2;      // 16MB
  unsigned short* Kb   = (unsigned short*)w; w += (size_t)M * C * 2;      // 16MB (Q+8M)
  unsigned short* Vt   = (unsigned short*)w; w += (size_t)M * C * 2;      // 16MB (Q+16M)
  unsigned short* Xb   = (unsigned short*)w; w += (size_t)M * C * 2;      // 16MB
  (void)Kb;
  // d_out (32MB) phases: [Wvb 2MB | Wot 2MB] -> S (bf16 32MB) -> final fp32
  unsigned short* Wvb  = (unsigned short*)d_out;               // Wv, cast only
  unsigned short* Wot  = (unsigned short*)d_out + (size_t)C * C;  // Wo^T
  unsigned short* S    = (unsigned short*)d_out;               // overwrites both
  unsigned short* Sn   = Q;  // normalized P, 32MB over dead Q+Kb (post-QK^T)

  // one-time: allow 128KB dynamic LDS for the 8-phase QKV GEMM
  static int smem_set = 0;
  if (!smem_set) {
    hipFuncSetAttribute(reinterpret_cast<const void*>(gemm_qkv8),
                        hipFuncAttributeMaxDynamicSharedMemorySize, 131072);
    smem_set = 1;
  }

  // prep: Wq->Wcat0, Wk->Wcat1 (T), Wv->Wvb (cast), Wo->Wot (T), X->Xb
  prep<<<dim3(32, 32, 12), dim3(32, 8), 0, stream>>>(X, Wq, Wk, Wv, Wo, Xb,
                                                     Wcat, Wvb, Wot, C);

  // WvoT[n][k] = sum_i Wot[n][i]*Wvb[k][i] = (Wv@Wo)^T[n][k] -> Wcat slot 2
  gemm_bt<unsigned short, 4><<<dim3(C / 128, C / 128, 1), dim3(256), 0, stream>>>(
      Wot, C, 0, Wvb, C, 0, Wcat + (size_t)2 * C * C, C, 0, C, 1.f, 0, 0, 0);

  // fused QKV: [8192 x 3072] = Xb @ Wcat^T-layout (V-slot = Wv@Wo)
  // 256x256 8-phase counted-vmcnt, aligned fragments, launch_bounds(512,1)
  gemm_qkv8<<<dim3((M / 256) * (3 * C / 256)), dim3(512), 131072, stream>>>(
      Xb, C, Wcat, C, Q, C);

  // S[b] = Q[b] @ K[b]^T / 32 — lower-tri 128-tiles (136 x 4), into d_out
  const int ntri = (T / 128) * (T / 128 + 1) / 2;
  gemm_bt<unsigned short, 8><<<dim3(ntri, 1, Bb), dim3(512), 0, stream>>>(
      Q, C, (long long)T * C, Kb, C, (long long)T * C,
      S, T, (long long)T * T, C, 0.03125f, 1, 0, 0);

  // causal softmax: S (d_out) -> Sn (ws, over dead Q+Kb)
  softmax_causal<<<M, 256, 0, stream>>>(S, Sn, T);

  // FINAL GEMM: Out[b] = P[b] @ (V@Wo)[b] — fp32 straight into d_out (R9b)
  gemm_bt<float, 8><<<dim3((C / 128) * (T / 128), 1, Bb), dim3(512), 0, stream>>>(
      Sn, T, (long long)T * T, Vt, T, (long long)C * T,
      (float*)d_out, C, (long long)T * C, T, 1.f, 0, 1, /*gx=*/C / 128);
}

// Round 7
// 244.130 us; speedup vs baseline: 1.0844x; 1.0683x over previous
//
#include <hip/hip_runtime.h>
#include <hip/hip_bf16.h>
#include <cmath>

// ---------------------------------------------------------------------------
// Causal single-head self-attention, B=4 T=2048 C=1024, fp32 in/out,
// bf16 MFMA internally.
// R1: LDS xor-swizzle (conflicts -> 0), causal tile skip + K-cap.
// R2: fused QKV projection (N=3072, V transposed in epilogue), XCD swizzle.
// R7/R8: Wo folded into V projection (out = P@(X@(Wv@Wo))), 70MB ws carve.
// R9b: memcpy elimination (softmax out-of-place, PV fp32 -> d_out): WIN.
// R9a/R10/R12/R13a: 256x256 8-phase QKV arc — ABANDONED after 5 rounds:
//   drain-variant 78.7us, counted-vmcnt raced (fragment/staging-half
//   misalignment, fixed in R12), aligned variant 100us (VGPR squeeze),
//   (512,1) variant 75.6us with VGPR_Count still pinned at 128, MfmaUtil 26%.
//   All >= gemm_qkv's 62.6us => permanent revert per decision rule.
// R13b: QK^T tri-index XCD-contiguous swizzle — WIN (~15us on the tri GEMM;
//   R14 total 260.8 despite qkv8 being 13us slower => non-QKV pool 200->185).
// R15: recombination of proven parts: gemm_qkv (62.6us) + R13b tri-swizzle
//   + R9b plumbing. Expected ~248us.
// ---------------------------------------------------------------------------

typedef __attribute__((ext_vector_type(8))) __bf16 bf16x8;
typedef __attribute__((ext_vector_type(8))) short short8;
typedef __attribute__((ext_vector_type(4))) float f32x4;

__device__ __forceinline__ unsigned short f2bf(float f) {
  union { float f; unsigned u; } v; v.f = f;
  unsigned u = v.u;
  u += ((u >> 16) & 1u) + 0x7fffu;   // round-to-nearest-even
  return (unsigned short)(u >> 16);
}
__device__ __forceinline__ float bf2f(unsigned short h) {
  union { unsigned u; float f; } v; v.u = ((unsigned)h) << 16;
  return v.f;
}

#define GLDS(gp, sp)                                                           \
  __builtin_amdgcn_global_load_lds(                                            \
      (const __attribute__((address_space(1))) void*)(gp),                     \
      (__attribute__((address_space(3))) void*)(sp), 16, 0, 0)

// ------------------------------- prep --------------------------------------
// z=0: Wq -> Wcat[0] (transpose+cast)   z=1: Wk -> Wcat[1] (transpose+cast)
// z=2: Wv -> Wvb     (CAST ONLY — must enter WvoT GEMM un-transposed!)
// z=3: Wo -> Wot     (transpose+cast)   z>=4: X -> Xb (cast)
__global__ void prep(const float* __restrict__ X,
                     const float* __restrict__ w0, const float* __restrict__ w1,
                     const float* __restrict__ w2, const float* __restrict__ w3,
                     unsigned short* __restrict__ Xb,
                     unsigned short* __restrict__ wcat,   // [2C][C] used
                     unsigned short* __restrict__ wvb,    // [C][C] plain cast
                     unsigned short* __restrict__ wot,    // [C][C] transposed
                     int n) {
  if (blockIdx.z == 2) {  // plain cast Wv
    int bx = blockIdx.x * 32, by = blockIdx.y * 32;
    int tx = threadIdx.x, ty = threadIdx.y;
#pragma unroll
    for (int i = 0; i < 32; i += 8) {
      size_t idx = (size_t)(by + ty + i) * n + bx + tx;
      wvb[idx] = f2bf(w2[idx]);
    }
  } else if (blockIdx.z < 4) {
    const float* src = blockIdx.z == 0 ? w0 : blockIdx.z == 1 ? w1 : w3;
    unsigned short* dst = blockIdx.z == 0 ? wcat
                          : blockIdx.z == 1 ? wcat + (size_t)n * n : wot;
    __shared__ float tile[32][33];
    int bx = blockIdx.x * 32, by = blockIdx.y * 32;
    int tx = threadIdx.x, ty = threadIdx.y;
#pragma unroll
    for (int i = 0; i < 32; i += 8)
      tile[ty + i][tx] = src[(size_t)(by + ty + i) * n + bx + tx];
    __syncthreads();
#pragma unroll
    for (int i = 0; i < 32; i += 8)
      dst[(size_t)(bx + ty + i) * n + by + tx] = f2bf(tile[tx][ty + i]);
  } else {
    const int bid = (blockIdx.z - 4) * 1024 + blockIdx.y * 32 + blockIdx.x;
    const int t = threadIdx.y * 32 + threadIdx.x;
    const int i = (bid * 256 + t) * 4;
    float4 f = *(const float4*)(X + i);
    ushort4 o = make_ushort4(f2bf(f.x), f2bf(f.y), f2bf(f.z), f2bf(f.w));
    *(ushort4*)(Xb + i) = o;
  }
}

// ------------------------------ GEMM (B^T) ---------------------------------
// C[m][n] = alpha * sum_k A[m][k] * Bt[n][k]
// 128x128 block tile, BK=64, 16x16x32 bf16 MFMA, LDS xor-swizzle (R1).
// NW=4: 256 thr, 4 waves of 64x64. NW=8: 512 thr, 8 waves of 32x64.
// tri : blockIdx.x is a lower-triangular tile index (XCD-swizzled, R13b).
// kcap: K_eff = min(K, m0+128) (causal PV truncation) + heavy-rows-first.
// gx>0: 1D grid, XCD-aware decode (8-row groups, bx-major, yy fastest).
template <typename OutT, int NW>
__global__ __launch_bounds__(NW * 64, NW / 2)
void gemm_bt(const unsigned short* __restrict__ A, int lda, long long sA,
             const unsigned short* __restrict__ B, int ldb, long long sB,
             OutT* __restrict__ Cp, int ldc, long long sC,
             int K, float alpha, int tri, int kcap, int gx) {
  A  += (long long)blockIdx.z * sA;
  B  += (long long)blockIdx.z * sB;
  Cp += (long long)blockIdx.z * sC;

  int by, bx;
  if (tri) {
    // XCD-contiguous remap (R13b): gridDim.x % 8 == 0 (136 = 8*17).
    int idx = blockIdx.x;
    idx = (idx & 7) * ((int)gridDim.x >> 3) + (idx >> 3);
    by = (int)((sqrtf(8.f * idx + 1.f) - 1.f) * 0.5f);
    while (by * (by + 1) / 2 > idx) --by;
    while ((by + 1) * (by + 2) / 2 <= idx) ++by;
    bx = idx - by * (by + 1) / 2;
  } else if (gx > 0) {
    const int id = blockIdx.x;
    const int gs = gx * 8;
    const int g = id / gs, r = id - g * gs;
    bx = r >> 3;
    by = g * 8 + (r & 7);
    if (kcap) by = (gridDim.x / gx) - 1 - by;  // heavy rows first
  } else {
    by = blockIdx.y;
    bx = blockIdx.x;
  }
  const int m0 = by * 128;
  const int n0 = bx * 128;
  const int Keff = kcap ? min(K, m0 + 128) : K;

  const int tid  = threadIdx.x;
  const int lane = tid & 63;
  const int w    = tid >> 6;
  const int wm   = (NW == 4) ? (w >> 1) * 64 : (w >> 1) * 32;
  const int wn   = (w & 1) * 64;
  const int quad = lane >> 4;
  const int l16  = lane & 15;
  constexpr int AI = (NW == 4) ? 4 : 2;   // A-fragment count per wave
  constexpr int NR = 128 / (NW * 8);      // staging rounds per tile

  __shared__ unsigned short As[8192];
  __shared__ unsigned short Bs[8192];

  f32x4 acc[AI][4];
#pragma unroll
  for (int i = 0; i < AI; ++i)
#pragma unroll
    for (int j = 0; j < 4; ++j)
      acc[i][j] = (f32x4){0.f, 0.f, 0.f, 0.f};

  const int srow = tid >> 3;
  const int scol = ((tid & 7) ^ (srow & 7)) * 8;
  const unsigned short* gA = A + (long long)(m0 + srow) * lda + scol;
  const unsigned short* gB = B + (long long)(n0 + srow) * ldb + scol;
  const int rsw = l16 & 7;

  for (int kt = 0; kt < Keff; kt += 64) {
    __syncthreads();
#pragma unroll
    for (int r = 0; r < NR; ++r) {
      GLDS(gA + (long long)(r * NW * 8) * lda + kt, As + r * NW * 512 + tid * 8);
      GLDS(gB + (long long)(r * NW * 8) * ldb + kt, Bs + r * NW * 512 + tid * 8);
    }
    __syncthreads();
#pragma unroll
    for (int ks = 0; ks < 2; ++ks) {
      bf16x8 af[AI], bfr[4];
#pragma unroll
      for (int i = 0; i < AI; ++i)
        af[i] = *(const bf16x8*)(As + (wm + i * 16 + l16) * 64 +
                                 ((ks * 4 + quad) ^ rsw) * 8);
#pragma unroll
      for (int j = 0; j < 4; ++j)
        bfr[j] = *(const bf16x8*)(Bs + (wn + j * 16 + l16) * 64 +
                                  ((ks * 4 + quad) ^ rsw) * 8);
#pragma unroll
      for (int i = 0; i < AI; ++i)
#pragma unroll
        for (int j = 0; j < 4; ++j)
          acc[i][j] = __builtin_amdgcn_mfma_f32_16x16x32_bf16(af[i], bfr[j],
                                                              acc[i][j], 0, 0, 0);
    }
  }

  // C/D layout (m89/m91 verified): col = lane&15, row = quad*4 + reg
#pragma unroll
  for (int i = 0; i < AI; ++i) {
#pragma unroll
    for (int j = 0; j < 4; ++j) {
      const int row = m0 + wm + i * 16 + quad * 4;
      const int col = n0 + wn + j * 16 + l16;
#pragma unroll
      for (int r = 0; r < 4; ++r) {
        float v = acc[i][j][r] * alpha;
        if constexpr (sizeof(OutT) == 2)
          Cp[(long long)(row + r) * ldc + col] = (OutT)f2bf(v);
        else
          Cp[(long long)(row + r) * ldc + col] = v;
      }
    }
  }
}

// ----------------------- QKV GEMM (128x128, 4 waves) -----------------------
// N=3072 fused; XCD swizzle via gx. Epilogue: Q | K (+8M) | V^T (+16M,
// Vt[b][c][t]). With Wcat slot 2 = WvoT, "V" is X@Wv@Wo.
// (R0-proven: 62.6us, MfmaUtil 34%.)
__global__ __launch_bounds__(256, 2)
void gemm_qkv(const unsigned short* __restrict__ A, int lda,
              const unsigned short* __restrict__ B, int ldb,
              unsigned short* __restrict__ Cp, int K, int gx) {
  const int id = blockIdx.x;
  const int gs = gx * 8;
  const int g = id / gs, r = id - g * gs;
  const int bx = r >> 3;
  const int by = g * 8 + (r & 7);
  const int m0 = by * 128;
  const int n0 = bx * 128;

  const int tid  = threadIdx.x;
  const int lane = tid & 63;
  const int w    = tid >> 6;
  const int wm   = (w >> 1) * 64;
  const int wn   = (w & 1) * 64;
  const int quad = lane >> 4;
  const int l16  = lane & 15;

  __shared__ unsigned short As[8192];
  __shared__ unsigned short Bs[8192];

  f32x4 acc[4][4];
#pragma unroll
  for (int i = 0; i < 4; ++i)
#pragma unroll
    for (int j = 0; j < 4; ++j)
      acc[i][j] = (f32x4){0.f, 0.f, 0.f, 0.f};

  const int srow = tid >> 3;
  const int scol = ((tid & 7) ^ (srow & 7)) * 8;
  const unsigned short* gA = A + (long long)(m0 + srow) * lda + scol;
  const unsigned short* gB = B + (long long)(n0 + srow) * ldb + scol;
  const int rsw = l16 & 7;

  for (int kt = 0; kt < K; kt += 64) {
    __syncthreads();
#pragma unroll
    for (int r2 = 0; r2 < 4; ++r2) {
      GLDS(gA + (long long)(r2 * 32) * lda + kt, As + r2 * 2048 + tid * 8);
      GLDS(gB + (long long)(r2 * 32) * ldb + kt, Bs + r2 * 2048 + tid * 8);
    }
    __syncthreads();
#pragma unroll
    for (int ks = 0; ks < 2; ++ks) {
      bf16x8 af[4], bfr[4];
#pragma unroll
      for (int i = 0; i < 4; ++i)
        af[i] = *(const bf16x8*)(As + (wm + i * 16 + l16) * 64 +
                                 ((ks * 4 + quad) ^ rsw) * 8);
#pragma unroll
      for (int j = 0; j < 4; ++j)
        bfr[j] = *(const bf16x8*)(Bs + (wn + j * 16 + l16) * 64 +
                                  ((ks * 4 + quad) ^ rsw) * 8);
#pragma unroll
      for (int i = 0; i < 4; ++i)
#pragma unroll
        for (int j = 0; j < 4; ++j)
          acc[i][j] = __builtin_amdgcn_mfma_f32_16x16x32_bf16(af[i], bfr[j],
                                                              acc[i][j], 0, 0, 0);
    }
  }

#pragma unroll
  for (int i = 0; i < 4; ++i) {
#pragma unroll
    for (int j = 0; j < 4; ++j) {
      const int row = m0 + wm + i * 16 + quad * 4;
      const int col = n0 + wn + j * 16 + l16;
      if (col >= 2048) {  // V(=X@Wv@Wo), stored transposed: Vt[b][c][t]
        const int b = row >> 11, t = row & 2047, cv = col - 2048;
        ushort4 o = make_ushort4(f2bf(acc[i][j][0]), f2bf(acc[i][j][1]),
                                 f2bf(acc[i][j][2]), f2bf(acc[i][j][3]));
        *(ushort4*)(Cp + 16777216LL + ((long long)(b * 1024 + cv)) * 2048 + t) = o;
      } else {  // Q (col<1024) or K (col in [1024,2048))
        unsigned short* dst = Cp + (col >= 1024 ? 8388608LL - 1024 : 0);
#pragma unroll
        for (int r2 = 0; r2 < 4; ++r2)
          dst[(long long)(row + r2) * 1024 + col] = f2bf(acc[i][j][r2]);
      }
    }
  }
}

// ------------------------- causal softmax (out-of-place) -------------------
// 128-granular limit (matches PV's Keff = m0+128 read window). Reads S from
// d_out, writes normalized P into ws (over dead Q+Kb) so PV can write fp32
// output directly into d_out (R9b: kills the 32MB d2d copy).
__global__ __launch_bounds__(256)
void softmax_causal(const unsigned short* __restrict__ Sin,
                    unsigned short* __restrict__ Sout, int T) {
  const long long row = blockIdx.x;
  const int t = (int)(row & (long long)(T - 1));
  const int limit = ((t >> 7) + 1) << 7;
  const unsigned short* pin = Sin + row * T;
  unsigned short* pout = Sout + row * T;
  const int tid  = threadIdx.x;
  const int base = tid * 8;
  const bool active = base < limit;

  short8 raw = {};
  if (active) raw = *(const short8*)(pin + base);
  float x[8];
  float mx = -1e30f;
#pragma unroll
  for (int j = 0; j < 8; ++j) {
    bool valid = active && (base + j) <= t;
    x[j] = valid ? bf2f((unsigned short)raw[j]) : -1e30f;
    mx = fmaxf(mx, x[j]);
  }
#pragma unroll
  for (int off = 32; off > 0; off >>= 1) mx = fmaxf(mx, __shfl_xor(mx, off));
  __shared__ float red[8];
  const int wv = tid >> 6;
  if ((tid & 63) == 0) red[wv] = mx;
  __syncthreads();
  mx = fmaxf(fmaxf(red[0], red[1]), fmaxf(red[2], red[3]));

  float sum = 0.f;
#pragma unroll
  for (int j = 0; j < 8; ++j) {
    bool valid = active && (base + j) <= t;
    x[j] = valid ? __expf(x[j] - mx) : 0.f;
    sum += x[j];
  }
#pragma unroll
  for (int off = 32; off > 0; off >>= 1) sum += __shfl_xor(sum, off);
  if ((tid & 63) == 0) red[4 + wv] = sum;
  __syncthreads();
  sum = red[4] + red[5] + red[6] + red[7];
  const float inv = 1.f / sum;

  if (active) {
    unsigned short out[8];
#pragma unroll
    for (int j = 0; j < 8; ++j) out[j] = f2bf(x[j] * inv);
    *(short8*)(pout + base) = *(const short8*)out;
  }
}

// ---------------------------------------------------------------------------
extern "C" void kernel_launch(void* const* d_in, const int* in_sizes, int n_in,
                              void* d_out, int out_size, void* d_ws,
                              size_t ws_size, hipStream_t stream) {
  (void)in_sizes; (void)n_in; (void)out_size; (void)ws_size;
  const int Bb = 4, T = 2048, C = 1024;
  const int M = Bb * T;  // 8192

  const float* X  = (const float*)d_in[0];
  const float* Wq = (const float*)d_in[1];
  const float* Wk = (const float*)d_in[2];
  const float* Wv = (const float*)d_in[3];
  const float* Wo = (const float*)d_in[4];

  // ws carve: 70MB (proven budget is >=72). Q/Kb/Vt contiguous triple.
  char* w = (char*)d_ws;
  unsigned short* Wcat = (unsigned short*)w; w += (size_t)3 * C * C * 2;  // 6MB
  unsigned short* Q    = (unsigned short*)w; w += (size_t)M * C * 2;      // 16MB
  unsigned short* Kb   = (unsigned short*)w; w += (size_t)M * C * 2;      // 16MB (Q+8M)
  unsigned short* Vt   = (unsigned short*)w; w += (size_t)M * C * 2;      // 16MB (Q+16M)
  unsigned short* Xb   = (unsigned short*)w; w += (size_t)M * C * 2;      // 16MB
  (void)Kb;
  // d_out (32MB) phases: [Wvb 2MB | Wot 2MB] -> S (bf16 32MB) -> final fp32
  unsigned short* Wvb  = (unsigned short*)d_out;               // Wv, cast only
  unsigned short* Wot  = (unsigned short*)d_out + (size_t)C * C;  // Wo^T
  unsigned short* S    = (unsigned short*)d_out;               // overwrites both
  unsigned short* Sn   = Q;  // normalized P, 32MB over dead Q+Kb (post-QK^T)

  // prep: Wq->Wcat0, Wk->Wcat1 (T), Wv->Wvb (cast), Wo->Wot (T), X->Xb
  prep<<<dim3(32, 32, 12), dim3(32, 8), 0, stream>>>(X, Wq, Wk, Wv, Wo, Xb,
                                                     Wcat, Wvb, Wot, C);

  // WvoT[n][k] = sum_i Wot[n][i]*Wvb[k][i] = (Wv@Wo)^T[n][k] -> Wcat slot 2
  gemm_bt<unsigned short, 4><<<dim3(C / 128, C / 128, 1), dim3(256), 0, stream>>>(
      Wot, C, 0, Wvb, C, 0, Wcat + (size_t)2 * C * C, C, 0, C, 1.f, 0, 0, 0);

  // fused QKV: [8192 x 3072] = Xb @ Wcat^T-layout (V-slot = Wv@Wo)
  gemm_qkv<<<dim3((3 * C / 128) * (M / 128)), dim3(256), 0, stream>>>(
      Xb, C, Wcat, C, Q, C, /*gx=*/3 * C / 128);

  // S[b] = Q[b] @ K[b]^T / 32 — lower-tri 128-tiles (136 x 4), XCD-swizzled
  const int ntri = (T / 128) * (T / 128 + 1) / 2;
  gemm_bt<unsigned short, 8><<<dim3(ntri, 1, Bb), dim3(512), 0, stream>>>(
      Q, C, (long long)T * C, Kb, C, (long long)T * C,
      S, T, (long long)T * T, C, 0.03125f, 1, 0, 0);

  // causal softmax: S (d_out) -> Sn (ws, over dead Q+Kb)
  softmax_causal<<<M, 256, 0, stream>>>(S, Sn, T);

  // FINAL GEMM: Out[b] = P[b] @ (V@Wo)[b] — fp32 straight into d_out (R9b)
  gemm_bt<float, 8><<<dim3((C / 128) * (T / 128), 1, Bb), dim3(512), 0, stream>>>(
      Sn, T, (long long)T * T, Vt, T, (long long)C * T,
      (float*)d_out, C, (long long)T * C, T, 1.f, 0, 1, /*gx=*/C / 128);
}